// Round 16
// baseline (321.985 us; speedup 1.0000x reference)
//
#include <hip/hip_runtime.h>
#include <hip/hip_bf16.h>

// AdaConv2d: per-sample conv, kernel = base * mask[label[b]] (oc-indep mask).
// B=64, IC=OC=64, H=W=112, 3x3, pad 1. fp32 in/out.
//
// Round 15: persistent-block counted-vmcnt pipeline. R11-R14 all ~120us,
// MfmaUtil 22% = the 2-phase stage/vmcnt(0)/barrier ceiling (m233): blocks
// can't overlap stage(next block) with compute(this block) at launch grain.
// New: grid=256 (1 block/CU), block=(b,x0), 512 thr (8 waves), loops 7
// y-tiles (16 rows x 32 px). stage(t+1) issued BEFORE compute(t); wait =
// s_waitcnt vmcnt(10) (10 gloads/wave/stage, uniform incl. tail), raw
// s_barrier (NOT __syncthreads -> would drain vmcnt(0)), sched_barrier(0)
// per rule #18. LDS 2 x 76.5KB double buffer.

#define HH 112
#define WW 112
#define ICn 64
#define OCn 64
#define FUSE_EPOCH 9
#define NPIX (HH * WW)
#define YP 114
#define PR 18                 // padded rows per 16-row tile
#define CHUNKS (4 * PR * 2 * 34)   // 4896 16B-chunks per buffer

typedef __attribute__((ext_vector_type(8)))  short  short8;
typedef __attribute__((ext_vector_type(8)))  unsigned short bf8;
typedef __attribute__((ext_vector_type(4)))  unsigned short bf4;
typedef __attribute__((ext_vector_type(16))) float  f32x16;
typedef unsigned int u32;

#define XT_ELEMS ((size_t)64 * 4 * YP * YP * 16)
#define XT_BYTES (XT_ELEMS * 2)
#define WF_BYTES ((size_t)4 * 64 * 576 * 2)

static __device__ __forceinline__ unsigned short f2bf(float v) {
    __hip_bfloat16 hb = __float2bfloat16(v);
    return *reinterpret_cast<unsigned short*>(&hb);
}

static __device__ __forceinline__ void gload16(const unsigned short* g, unsigned short* l) {
    __builtin_amdgcn_global_load_lds(
        (const __attribute__((address_space(1))) u32*)g,
        (__attribute__((address_space(3))) u32*)l, 16, 0, 0);
}

// -------- fused weights: wf2[d][ck][t][h][oc][8e], ic = ck*16+h*8+e --------
__global__ __launch_bounds__(256)
void fuse_w_kernel(const float* __restrict__ kb, const float* __restrict__ km,
                   unsigned short* __restrict__ wf2)
{
    int idx = blockIdx.x * 256 + threadIdx.x;
    if (idx >= 4 * 4 * 9 * 2 * 64 * 8) return;
    int e  = idx & 7;
    int oc = (idx >> 3) & 63;
    int h  = (idx >> 9) & 1;
    int r  = idx >> 10;          // t + 9*(ck + 4*d)
    int t  = r % 9; r /= 9;
    int ck = r & 3;
    int d  = r >> 2;
    int ic = ck * 16 + h * 8 + e;
    wf2[idx] = f2bf(kb[(oc * ICn + ic) * 9 + t] * km[(d * ICn + ic) * 9 + t]);
}

// ---------------- zero the halo of each (b,ck) plane ----------------
__global__ __launch_bounds__(256)
void pad_zero_kernel(unsigned short* __restrict__ Xt)
{
    const int plane = blockIdx.x;   // 0..255 = b*4+ck
    const int tid = threadIdx.x;
    const size_t base = (size_t)plane * YP * YP * 16;
    const bf8 z = bf8{0,0,0,0,0,0,0,0};
    for (int i = tid; i < YP * 2; i += 256) {
        *reinterpret_cast<bf8*>(Xt + base + (size_t)i * 8) = z;
        *reinterpret_cast<bf8*>(Xt + base + (size_t)113 * YP * 16 + (size_t)i * 8) = z;
    }
    for (int i = tid; i < 112 * 2 * 2; i += 256) {
        int j = i & 1, col = (i >> 1) & 1, yp = 1 + (i >> 2);
        size_t off = base + ((size_t)yp * YP + col * 113) * 16 + (size_t)j * 8;
        *reinterpret_cast<bf8*>(Xt + off) = z;
    }
}

// ---- transpose x[b][ic][y][x] fp32 -> Xt[b][ic/16][y+1][x+1][ic%16] bf16 ----
__global__ __launch_bounds__(256, 4)
void transpose_kernel(const float* __restrict__ x, unsigned short* __restrict__ Xt)
{
    __shared__ unsigned short T[56][68];
    const int tid = threadIdx.x;
    const int xh = blockIdx.x;      // 0..1 -> x0 = 0,56
    const int y  = blockIdx.y;      // 0..111
    const int b  = blockIdx.z;      // 0..63
    const int x0 = xh * 56;

    for (int i = tid; i < 64 * 14; i += 256) {       // 64 ic x 14 float4
        int ic = i / 14, c4 = i - ic * 14;
        const float4* p = reinterpret_cast<const float4*>(
            x + (((size_t)b * ICn + ic) * HH + y) * WW + x0 + c4 * 4);
        float4 v = *p;
        T[c4 * 4 + 0][ic] = f2bf(v.x);
        T[c4 * 4 + 1][ic] = f2bf(v.y);
        T[c4 * 4 + 2][ic] = f2bf(v.z);
        T[c4 * 4 + 3][ic] = f2bf(v.w);
    }
    __syncthreads();
    for (int i = tid; i < 56 * 16; i += 256) {       // 56 x  x 16 bf4
        int xx = i >> 4, k = i & 15;
        bf4 w = *reinterpret_cast<bf4*>(&T[xx][k * 4]);
        int ck = k >> 2, q = k & 3;
        *reinterpret_cast<bf4*>(
            Xt + ((((size_t)b * 4 + ck) * YP + y + 1) * YP + (x0 + xx + 1)) * 16 + q * 4) = w;
    }
}

// ------- main: persistent blocks, 7-tile loop, counted-vmcnt pipeline -------
__global__ __launch_bounds__(512, 2)
void adaconv_main(const unsigned short* __restrict__ Xt,
                  const unsigned short* __restrict__ wf2,
                  const int* __restrict__ label,
                  const int* __restrict__ epoch,
                  float* __restrict__ out)
{
    __shared__ unsigned short Bs[2][CHUNKS * 8];   // 2 x 76.5 KiB

    const int tid  = threadIdx.x;                  // 0..511
    const int w    = tid >> 6;                     // wave 0..7
    const int lane = tid & 63;
    const int ln   = lane & 31;
    const int h    = lane >> 5;
    const int b    = blockIdx.x >> 2;
    const int x0   = (blockIdx.x & 3) * 32;

    int d = (epoch[0] >= FUSE_EPOCH) ? 0 : label[b];
    d &= 3;
    const unsigned short* Wd = wf2 + (size_t)d * 36864;
    const int aoff = h * 512 + ln * 8;

    // stage one 16-row tile (padded rows y0..y0+17) into Bs[buf].
    // Exactly 10 gload_lds per WAVE (9 full rounds + 36-chunk tail/wave).
    auto stage = [&](int buf, int y0) {
        #pragma unroll
        for (int r = 0; r < 9; ++r) {
            int c = r * 512 + tid;
            int px = c % 34; int q = c / 34;
            int hh = q & 1;  q >>= 1;
            int lr = q % PR; int ck = q / PR;
            int yp = y0 + lr;                        // <= 113
            int xp = x0 + px; if (xp > 113) xp = 113;
            const unsigned short* g =
                Xt + ((((size_t)b * 4 + ck) * YP + yp) * YP + xp) * 16 + hh * 8;
            gload16(g, &Bs[buf][(size_t)(r * 512 + w * 64) * 8]);
        }
        {   // tail: 288 chunks = 36 per wave (lanes 0..35 active; 1 instr/wave)
            int c = 9 * 512 + w * 36 + lane;
            if (lane < 36) {
                int px = c % 34; int q = c / 34;
                int hh = q & 1;  q >>= 1;
                int lr = q % PR; int ck = q / PR;
                int yp = y0 + lr;
                int xp = x0 + px; if (xp > 113) xp = 113;
                const unsigned short* g =
                    Xt + ((((size_t)b * 4 + ck) * YP + yp) * YP + xp) * 16 + hh * 8;
                gload16(g, &Bs[buf][(size_t)(9 * 512 + w * 36) * 8]);
            }
        }
    };

    stage(0, 0);
    int cur = 0;

    for (int ty = 0; ty < 7; ++ty) {
        const int y0 = ty * 16;
        if (ty < 6) {
            stage(cur ^ 1, y0 + 16);                       // 10 new gloads/wave
            asm volatile("s_waitcnt vmcnt(10)" ::: "memory");  // cur's 10 done
        } else {
            asm volatile("s_waitcnt vmcnt(0)" ::: "memory");
        }
        __builtin_amdgcn_s_barrier();
        __builtin_amdgcn_sched_barrier(0);

        f32x16 acc[2][2];
        #pragma unroll
        for (int m = 0; m < 2; ++m)
            #pragma unroll
            for (int rj = 0; rj < 2; ++rj)
                #pragma unroll
                for (int k = 0; k < 16; ++k) acc[m][rj][k] = 0.f;

        const unsigned short* Bb = &Bs[cur][0];

        #pragma unroll
        for (int ck = 0; ck < 4; ++ck) {
            // batched A-preload (L2-hot: same weights all 7 tiles)
            short8 a[9][2];
            const unsigned short* Wt = Wd + ck * 9216;
            #pragma unroll
            for (int t = 0; t < 9; ++t) {
                a[t][0] = *reinterpret_cast<const short8*>(Wt + t * 1024 + aoff);
                a[t][1] = *reinterpret_cast<const short8*>(Wt + t * 1024 + aoff + 256);
            }
            // 12 B-fragments: padded rows 2w..2w+3, kw 0..2
            short8 frag[4][3];
            #pragma unroll
            for (int rf = 0; rf < 4; ++rf)
                #pragma unroll
                for (int kw = 0; kw < 3; ++kw)
                    frag[rf][kw] = *reinterpret_cast<const short8*>(
                        &Bb[(size_t)((((ck * PR + 2 * w + rf) * 2 + h) * 34) + ln + kw) * 8]);

            __builtin_amdgcn_s_setprio(1);
            #pragma unroll
            for (int kh = 0; kh < 3; ++kh) {
                #pragma unroll
                for (int kw = 0; kw < 3; ++kw) {
                    const int t = kh * 3 + kw;
                    #pragma unroll
                    for (int rj = 0; rj < 2; ++rj) {
                        acc[0][rj] = __builtin_amdgcn_mfma_f32_32x32x16_bf16(a[t][0], frag[rj + kh][kw], acc[0][rj], 0, 0, 0);
                        acc[1][rj] = __builtin_amdgcn_mfma_f32_32x32x16_bf16(a[t][1], frag[rj + kh][kw], acc[1][rj], 0, 0, 0);
                    }
                }
            }
            __builtin_amdgcn_s_setprio(0);
        }

        // store: oc = m*32 + (reg&3) + 8*(reg>>2) + 4*h ; wave rows y0+2w..+1
        const int xg = x0 + ln;
        if (xg < WW) {
            #pragma unroll
            for (int m = 0; m < 2; ++m) {
                #pragma unroll
                for (int rj = 0; rj < 2; ++rj) {
                    const int yg = y0 + 2 * w + rj;
                    float* ob = out + ((size_t)b * OCn + m * 32 + 4 * h) * NPIX + (size_t)yg * WW + xg;
                    #pragma unroll
                    for (int reg = 0; reg < 16; ++reg) {
                        int row = (reg & 3) + 8 * (reg >> 2);
                        ob[(size_t)row * NPIX] = acc[m][rj][reg];
                    }
                }
            }
        }
        __builtin_amdgcn_s_barrier();   // all reads of Bs[cur] done before re-stage
        cur ^= 1;
    }
}

// ---------------- fallback (round-5 structure, no ws) ----------------
#define ICP 24
#define WSTRIDE 152
__global__ __launch_bounds__(256, 2)
void adaconv_fallback(const float* __restrict__ x,
                      const float* __restrict__ kb,
                      const float* __restrict__ km,
                      const int* __restrict__ label,
                      const int* __restrict__ epoch,
                      float* __restrict__ out)
{
    __shared__ unsigned short Xs[18][34][ICP];
    __shared__ unsigned short Ws[64][WSTRIDE];

    const int tid = threadIdx.x;
    const int b   = blockIdx.y;
    const int bx  = blockIdx.x & 3;
    const int byy = blockIdx.x >> 2;
    const int x0 = bx * 32, y0 = byy * 16;

    int d = (epoch[0] >= FUSE_EPOCH) ? 0 : label[b];
    d &= 3;

    const int w    = tid >> 6;
    const int lane = tid & 63;
    const int ln   = lane & 31;
    const int h    = lane >> 5;

    f32x16 acc[2][4];
    #pragma unroll
    for (int m = 0; m < 2; ++m)
        #pragma unroll
        for (int j = 0; j < 4; ++j)
            #pragma unroll
            for (int k = 0; k < 16; ++k) acc[m][j][k] = 0.f;

    const float* xb = x + (size_t)b * ICn * HH * WW;

    for (int ck = 0; ck < 4; ++ck) {
        const int icb = ck * 16;
        __syncthreads();
        for (int idx = tid; idx < 18 * 34 * 16; idx += 256) {
            int ic  = idx / 612;
            int rem = idx - ic * 612;
            int r   = rem / 34;
            int c   = rem - r * 34;
            int gy = y0 - 1 + r, gx = x0 - 1 + c;
            float v = 0.f;
            if ((unsigned)gy < HH && (unsigned)gx < WW)
                v = xb[(size_t)(icb + ic) * (HH * WW) + gy * WW + gx];
            Xs[r][c][ic] = f2bf(v);
        }
        for (int i = tid; i < 9216; i += 256) {
            int ic_ = i & 15;
            int tt  = (i >> 4) % 9;
            int oc  = i / 144;
            int ic  = icb + ic_;
            Ws[oc][tt * 16 + ic_] = f2bf(kb[(oc * ICn + ic) * 9 + tt] * km[(d * ICn + ic) * 9 + tt]);
        }
        __syncthreads();
        #pragma unroll
        for (int kh = 0; kh < 3; ++kh)
            #pragma unroll
            for (int kw = 0; kw < 3; ++kw) {
                const int t = kh * 3 + kw;
                short8 a0 = *reinterpret_cast<const short8*>(&Ws[ln][t * 16 + h * 8]);
                short8 a1 = *reinterpret_cast<const short8*>(&Ws[32 + ln][t * 16 + h * 8]);
                #pragma unroll
                for (int rj = 0; rj < 4; ++rj) {
                    short8 bb = *reinterpret_cast<const short8*>(&Xs[4 * w + rj + kh][ln + kw][h * 8]);
                    acc[0][rj] = __builtin_amdgcn_mfma_f32_32x32x16_bf16(a0, bb, acc[0][rj], 0, 0, 0);
                    acc[1][rj] = __builtin_amdgcn_mfma_f32_32x32x16_bf16(a1, bb, acc[1][rj], 0, 0, 0);
                }
            }
    }

    const int xg = x0 + ln;
    if (xg < WW) {
        #pragma unroll
        for (int m = 0; m < 2; ++m)
            #pragma unroll
            for (int rj = 0; rj < 4; ++rj) {
                const int yg = y0 + 4 * w + rj;
                #pragma unroll
                for (int reg = 0; reg < 16; ++reg) {
                    const int row = (reg & 3) + 8 * (reg >> 2) + 4 * h;
                    out[(((size_t)b * OCn + m * 32 + row) * HH + yg) * WW + xg] = acc[m][rj][reg];
                }
            }
    }
}

extern "C" void kernel_launch(void* const* d_in, const int* in_sizes, int n_in,
                              void* d_out, int out_size, void* d_ws, size_t ws_size,
                              hipStream_t stream) {
    const float* x  = (const float*)d_in[0];
    const float* kb = (const float*)d_in[1];
    const float* km = (const float*)d_in[2];
    const int*   lb = (const int*)d_in[3];
    const int*   ep = (const int*)d_in[4];
    float* out = (float*)d_out;

    if (ws_size >= XT_BYTES + WF_BYTES) {
        unsigned short* Xt  = (unsigned short*)d_ws;
        unsigned short* wf2 = (unsigned short*)((char*)d_ws + XT_BYTES);
        fuse_w_kernel<<<576, 256, 0, stream>>>(kb, km, wf2);
        pad_zero_kernel<<<256, 256, 0, stream>>>(Xt);
        transpose_kernel<<<dim3(2, HH, 64), 256, 0, stream>>>(x, Xt);
        adaconv_main<<<256, 512, 0, stream>>>(Xt, wf2, lb, ep, out);
    } else {
        adaconv_fallback<<<dim3(28, 64), 256, 0, stream>>>(x, kb, km, lb, ep, out);
    }
}

// Round 17
// 192.035 us; speedup vs baseline: 1.6767x; 1.6767x over previous
//
#include <hip/hip_runtime.h>
#include <hip/hip_bf16.h>

// AdaConv2d: per-sample conv, kernel = base * mask[label[b]] (oc-indep mask).
// B=64, IC=OC=64, H=W=112, 3x3, pad 1. fp32 in/out.
//
// Round 16: LDS-only compute phase (m97 property). R11-R15 all ~116-123us,
// MfmaUtil 22%: every variant still issued ~72 global A-loads per wave in
// the compute phase (R14/R15 reg-preloads never stuck: compiler re-sank or
// spilled). Fix: stage A into LDS too. Full-64oc A (73.7KB) doesn't fit ->
// split oc across blocks: block = 32oc x 8rows x 32px, LDS = B 43.5KB
// (exact) + A 36.9KB = 80.4KB -> 2 blocks/CU. Single vmcnt(0)+barrier,
// then 4ck x {21 ds_reads + 18 MFMAs}/wave with zero global loads.

#define HH 112
#define WW 112
#define ICn 64
#define OCn 64
#define FUSE_EPOCH 9
#define NPIX (HH * WW)
#define YP 114

#define BCH 2720          // B chunks: 4ck x 10lr x 2hh x 34px
#define ACH 2304          // A chunks: 4ck x 9t x 2hh x 32oc
#define LCH (BCH + ACH)   // 5024 chunks x 16B = 80384 B

typedef __attribute__((ext_vector_type(8)))  short  short8;
typedef __attribute__((ext_vector_type(8)))  unsigned short bf8;
typedef __attribute__((ext_vector_type(4)))  unsigned short bf4;
typedef __attribute__((ext_vector_type(16))) float  f32x16;
typedef unsigned int u32;

#define XT_ELEMS ((size_t)64 * 4 * YP * YP * 16)
#define XT_BYTES (XT_ELEMS * 2)
#define WF_BYTES ((size_t)4 * 64 * 576 * 2)

static __device__ __forceinline__ unsigned short f2bf(float v) {
    __hip_bfloat16 hb = __float2bfloat16(v);
    return *reinterpret_cast<unsigned short*>(&hb);
}

static __device__ __forceinline__ void gload16(const unsigned short* g, unsigned short* l) {
    __builtin_amdgcn_global_load_lds(
        (const __attribute__((address_space(1))) u32*)g,
        (__attribute__((address_space(3))) u32*)l, 16, 0, 0);
}

// -------- fused weights: wf2[d][ck][t][h][oc][8e], ic = ck*16+h*8+e --------
__global__ __launch_bounds__(256)
void fuse_w_kernel(const float* __restrict__ kb, const float* __restrict__ km,
                   unsigned short* __restrict__ wf2)
{
    int idx = blockIdx.x * 256 + threadIdx.x;
    if (idx >= 4 * 4 * 9 * 2 * 64 * 8) return;
    int e  = idx & 7;
    int oc = (idx >> 3) & 63;
    int h  = (idx >> 9) & 1;
    int r  = idx >> 10;          // t + 9*(ck + 4*d)
    int t  = r % 9; r /= 9;
    int ck = r & 3;
    int d  = r >> 2;
    int ic = ck * 16 + h * 8 + e;
    wf2[idx] = f2bf(kb[(oc * ICn + ic) * 9 + t] * km[(d * ICn + ic) * 9 + t]);
}

// ---------------- zero the halo of each (b,ck) plane ----------------
__global__ __launch_bounds__(256)
void pad_zero_kernel(unsigned short* __restrict__ Xt)
{
    const int plane = blockIdx.x;   // 0..255 = b*4+ck
    const int tid = threadIdx.x;
    const size_t base = (size_t)plane * YP * YP * 16;
    const bf8 z = bf8{0,0,0,0,0,0,0,0};
    for (int i = tid; i < YP * 2; i += 256) {
        *reinterpret_cast<bf8*>(Xt + base + (size_t)i * 8) = z;
        *reinterpret_cast<bf8*>(Xt + base + (size_t)113 * YP * 16 + (size_t)i * 8) = z;
    }
    for (int i = tid; i < 112 * 2 * 2; i += 256) {
        int j = i & 1, col = (i >> 1) & 1, yp = 1 + (i >> 2);
        size_t off = base + ((size_t)yp * YP + col * 113) * 16 + (size_t)j * 8;
        *reinterpret_cast<bf8*>(Xt + off) = z;
    }
}

// ---- transpose x[b][ic][y][x] fp32 -> Xt[b][ic/16][y+1][x+1][ic%16] bf16 ----
__global__ __launch_bounds__(256, 4)
void transpose_kernel(const float* __restrict__ x, unsigned short* __restrict__ Xt)
{
    __shared__ unsigned short T[56][68];
    const int tid = threadIdx.x;
    const int xh = blockIdx.x;      // 0..1 -> x0 = 0,56
    const int y  = blockIdx.y;      // 0..111
    const int b  = blockIdx.z;      // 0..63
    const int x0 = xh * 56;

    for (int i = tid; i < 64 * 14; i += 256) {       // 64 ic x 14 float4
        int ic = i / 14, c4 = i - ic * 14;
        const float4* p = reinterpret_cast<const float4*>(
            x + (((size_t)b * ICn + ic) * HH + y) * WW + x0 + c4 * 4);
        float4 v = *p;
        T[c4 * 4 + 0][ic] = f2bf(v.x);
        T[c4 * 4 + 1][ic] = f2bf(v.y);
        T[c4 * 4 + 2][ic] = f2bf(v.z);
        T[c4 * 4 + 3][ic] = f2bf(v.w);
    }
    __syncthreads();
    for (int i = tid; i < 56 * 16; i += 256) {       // 56 x  x 16 bf4
        int xx = i >> 4, k = i & 15;
        bf4 w = *reinterpret_cast<bf4*>(&T[xx][k * 4]);
        int ck = k >> 2, q = k & 3;
        *reinterpret_cast<bf4*>(
            Xt + ((((size_t)b * 4 + ck) * YP + y + 1) * YP + (x0 + xx + 1)) * 16 + q * 4) = w;
    }
}

// ------- main: implicit GEMM, 32-oc blocks, LDS-only compute phase -------
__global__ __launch_bounds__(256, 2)
void adaconv_main(const unsigned short* __restrict__ Xt,
                  const unsigned short* __restrict__ wf2,
                  const int* __restrict__ label,
                  const int* __restrict__ epoch,
                  float* __restrict__ out)
{
    __shared__ unsigned short L[LCH * 8];   // 80384 B: B chunks then A chunks

    const int tid   = threadIdx.x;
    const int b     = blockIdx.y;
    const int ohalf = blockIdx.x & 1;
    const int xt    = (blockIdx.x >> 1) & 3;
    const int yt    = blockIdx.x >> 3;           // 0..13
    const int x0 = xt * 32, y0 = yt * 8;
    const int w     = tid >> 6;
    const int lane  = tid & 63;
    const int ln    = lane & 31;
    const int h     = lane >> 5;

    int d = (epoch[0] >= FUSE_EPOCH) ? 0 : label[b];
    d &= 3;
    const unsigned short* Wd = wf2 + (size_t)d * 36864 + ohalf * 256;

    f32x16 acc[2];
    #pragma unroll
    for (int rj = 0; rj < 2; ++rj)
        #pragma unroll
        for (int k = 0; k < 16; ++k) acc[rj][k] = 0.f;

    // ---- stage B: 2720 chunks (ck, lr0..9, hh, px0..33) ----
    #pragma unroll
    for (int r = 0; r < 11; ++r) {
        int c = r * 256 + tid;
        if (c < BCH) {
            int ck = c / 680;
            int cw = c - ck * 680;
            int lr = cw / 68;
            int rem = cw - lr * 68;
            int hh = rem / 34;
            int px = rem - hh * 34;
            int yp = y0 + lr;                     // <= 113
            int xp = x0 + px; if (xp > 113) xp = 113;
            const unsigned short* g =
                Xt + ((((size_t)b * 4 + ck) * YP + yp) * YP + xp) * 16 + hh * 8;
            gload16(g, &L[(size_t)(r * 256 + w * 64) * 8]);
        }
    }
    // ---- stage A: 2304 chunks (ck, t, hh, oc32) -- exact 9 rounds ----
    #pragma unroll
    for (int r = 0; r < 9; ++r) {
        int c = r * 256 + tid;
        int ck = c / 576;
        int cw = c - ck * 576;
        int t  = cw / 64;
        int rem = cw - t * 64;
        int hh = rem >> 5;
        int j  = rem & 31;
        const unsigned short* g = Wd + ck * 9216 + t * 1024 + hh * 512 + j * 8;
        gload16(g, &L[(size_t)(BCH + r * 256 + w * 64) * 8]);
    }
    __syncthreads();   // single drain

    // ---- compute: 4ck x {12 B-frag + 9 A ds_reads, 18 MFMAs}, LDS-only ----
    #pragma unroll
    for (int ck = 0; ck < 4; ++ck) {
        short8 frag[4][3];
        #pragma unroll
        for (int rf = 0; rf < 4; ++rf)
            #pragma unroll
            for (int kw = 0; kw < 3; ++kw)
                frag[rf][kw] = *reinterpret_cast<const short8*>(
                    &L[(size_t)(ck * 680 + (2 * w + rf) * 68 + h * 34 + ln + kw) * 8]);
        short8 a[9];
        #pragma unroll
        for (int t = 0; t < 9; ++t)
            a[t] = *reinterpret_cast<const short8*>(
                &L[(size_t)(BCH + ck * 576 + t * 64 + h * 32 + ln) * 8]);

        __builtin_amdgcn_s_setprio(1);
        #pragma unroll
        for (int kh = 0; kh < 3; ++kh)
            #pragma unroll
            for (int kw = 0; kw < 3; ++kw) {
                const int t = kh * 3 + kw;
                #pragma unroll
                for (int rj = 0; rj < 2; ++rj)
                    acc[rj] = __builtin_amdgcn_mfma_f32_32x32x16_bf16(a[t], frag[rj + kh][kw], acc[rj], 0, 0, 0);
            }
        __builtin_amdgcn_s_setprio(0);
    }

    // ---- store: oc = ohalf*32 + (reg&3) + 8*(reg>>2) + 4*h ----
    const int xg = x0 + ln;
    if (xg < WW) {
        #pragma unroll
        for (int rj = 0; rj < 2; ++rj) {
            const int yg = y0 + 2 * w + rj;
            float* ob = out + ((size_t)b * OCn + ohalf * 32 + 4 * h) * NPIX + (size_t)yg * WW + xg;
            #pragma unroll
            for (int reg = 0; reg < 16; ++reg) {
                int row = (reg & 3) + 8 * (reg >> 2);
                ob[(size_t)row * NPIX] = acc[rj][reg];
            }
        }
    }
}

// ---------------- fallback (round-5 structure, no ws) ----------------
#define ICP 24
#define WSTRIDE 152
__global__ __launch_bounds__(256, 2)
void adaconv_fallback(const float* __restrict__ x,
                      const float* __restrict__ kb,
                      const float* __restrict__ km,
                      const int* __restrict__ label,
                      const int* __restrict__ epoch,
                      float* __restrict__ out)
{
    __shared__ unsigned short Xs[18][34][ICP];
    __shared__ unsigned short Ws[64][WSTRIDE];

    const int tid = threadIdx.x;
    const int b   = blockIdx.y;
    const int bx  = blockIdx.x & 3;
    const int byy = blockIdx.x >> 2;
    const int x0 = bx * 32, y0 = byy * 16;

    int d = (epoch[0] >= FUSE_EPOCH) ? 0 : label[b];
    d &= 3;

    const int w    = tid >> 6;
    const int lane = tid & 63;
    const int ln   = lane & 31;
    const int h    = lane >> 5;

    f32x16 acc[2][4];
    #pragma unroll
    for (int m = 0; m < 2; ++m)
        #pragma unroll
        for (int j = 0; j < 4; ++j)
            #pragma unroll
            for (int k = 0; k < 16; ++k) acc[m][j][k] = 0.f;

    const float* xb = x + (size_t)b * ICn * HH * WW;

    for (int ck = 0; ck < 4; ++ck) {
        const int icb = ck * 16;
        __syncthreads();
        for (int idx = tid; idx < 18 * 34 * 16; idx += 256) {
            int ic  = idx / 612;
            int rem = idx - ic * 612;
            int r   = rem / 34;
            int c   = rem - r * 34;
            int gy = y0 - 1 + r, gx = x0 - 1 + c;
            float v = 0.f;
            if ((unsigned)gy < HH && (unsigned)gx < WW)
                v = xb[(size_t)(icb + ic) * (HH * WW) + gy * WW + gx];
            Xs[r][c][ic] = f2bf(v);
        }
        for (int i = tid; i < 9216; i += 256) {
            int ic_ = i & 15;
            int tt  = (i >> 4) % 9;
            int oc  = i / 144;
            int ic  = icb + ic_;
            Ws[oc][tt * 16 + ic_] = f2bf(kb[(oc * ICn + ic) * 9 + tt] * km[(d * ICn + ic) * 9 + tt]);
        }
        __syncthreads();
        #pragma unroll
        for (int kh = 0; kh < 3; ++kh)
            #pragma unroll
            for (int kw = 0; kw < 3; ++kw) {
                const int t = kh * 3 + kw;
                short8 a0 = *reinterpret_cast<const short8*>(&Ws[ln][t * 16 + h * 8]);
                short8 a1 = *reinterpret_cast<const short8*>(&Ws[32 + ln][t * 16 + h * 8]);
                #pragma unroll
                for (int rj = 0; rj < 4; ++rj) {
                    short8 bb = *reinterpret_cast<const short8*>(&Xs[4 * w + rj + kh][ln + kw][h * 8]);
                    acc[0][rj] = __builtin_amdgcn_mfma_f32_32x32x16_bf16(a0, bb, acc[0][rj], 0, 0, 0);
                    acc[1][rj] = __builtin_amdgcn_mfma_f32_32x32x16_bf16(a1, bb, acc[1][rj], 0, 0, 0);
                }
            }
    }

    const int xg = x0 + ln;
    if (xg < WW) {
        #pragma unroll
        for (int m = 0; m < 2; ++m)
            #pragma unroll
            for (int rj = 0; rj < 4; ++rj) {
                const int yg = y0 + 4 * w + rj;
                #pragma unroll
                for (int reg = 0; reg < 16; ++reg) {
                    const int row = (reg & 3) + 8 * (reg >> 2) + 4 * h;
                    out[(((size_t)b * OCn + m * 32 + row) * HH + yg) * WW + xg] = acc[m][rj][reg];
                }
            }
    }
}

extern "C" void kernel_launch(void* const* d_in, const int* in_sizes, int n_in,
                              void* d_out, int out_size, void* d_ws, size_t ws_size,
                              hipStream_t stream) {
    const float* x  = (const float*)d_in[0];
    const float* kb = (const float*)d_in[1];
    const float* km = (const float*)d_in[2];
    const int*   lb = (const int*)d_in[3];
    const int*   ep = (const int*)d_in[4];
    float* out = (float*)d_out;

    if (ws_size >= XT_BYTES + WF_BYTES) {
        unsigned short* Xt  = (unsigned short*)d_ws;
        unsigned short* wf2 = (unsigned short*)((char*)d_ws + XT_BYTES);
        fuse_w_kernel<<<576, 256, 0, stream>>>(kb, km, wf2);
        pad_zero_kernel<<<256, 256, 0, stream>>>(Xt);
        transpose_kernel<<<dim3(2, HH, 64), 256, 0, stream>>>(x, Xt);
        adaconv_main<<<dim3(112, 64), 256, 0, stream>>>(Xt, wf2, lb, ep, out);
    } else {
        adaconv_fallback<<<dim3(28, 64), 256, 0, stream>>>(x, kb, km, lb, ep, out);
    }
}

// Round 18
// 180.964 us; speedup vs baseline: 1.7793x; 1.0612x over previous
//
#include <hip/hip_runtime.h>
#include <hip/hip_bf16.h>

// AdaConv2d: per-sample conv, kernel = base * mask[label[b]] (oc-indep mask).
// B=64, IC=OC=64, H=W=112, 3x3, pad 1. fp32 in/out.
//
// Round 17: m97-shape register tiling. R16 diagnosis: per-CU streams MFMA 27 /
// LDS-read 47 / stage 32 / write 33 / VALU 34 us, serial (sum=130=observed).
// Fix the dominant two: (1) wave = 64oc x 64px = 2x2 of 32x32 accs -> 4 MFMA
// per 4 ds_read_b128 (2x better reuse); (2) staging addresses precomputed
// once (no div chains), frag reads = base + imm offset (zero compute VALU).
// Block = 4 waves, 4rows x 64px x 64oc; A+B per-ck in 31KB dbuf (62KB LDS,
// 2 blocks/CU), stage-ahead + one __syncthreads per ck (m97 2-phase).

#define HH 112
#define WW 112
#define ICn 64
#define OCn 64
#define FUSE_EPOCH 9
#define NPIX (HH * WW)
#define YP 114

#define BROWS 6
#define BCOLS 66
#define BCHK (BROWS * 2 * BCOLS)   // 792 B-chunks (16B each)
#define ACHK 1152                  // A-chunks: 9t x 2hh x 64oc
#define TCHK (BCHK + ACHK)         // 1944 chunks -> 31104 B per buffer

typedef __attribute__((ext_vector_type(8)))  short  short8;
typedef __attribute__((ext_vector_type(8)))  unsigned short bf8;
typedef __attribute__((ext_vector_type(4)))  unsigned short bf4;
typedef __attribute__((ext_vector_type(16))) float  f32x16;
typedef unsigned int u32;

#define XT_ELEMS ((size_t)64 * 4 * YP * YP * 16)
#define XT_BYTES (XT_ELEMS * 2)
#define WF_BYTES ((size_t)4 * 64 * 576 * 2)

static __device__ __forceinline__ unsigned short f2bf(float v) {
    __hip_bfloat16 hb = __float2bfloat16(v);
    return *reinterpret_cast<unsigned short*>(&hb);
}

static __device__ __forceinline__ void gload16(const unsigned short* g, unsigned short* l) {
    __builtin_amdgcn_global_load_lds(
        (const __attribute__((address_space(1))) u32*)g,
        (__attribute__((address_space(3))) u32*)l, 16, 0, 0);
}

// -------- fused weights: wf2[d][ck][t][h][oc][8e], ic = ck*16+h*8+e --------
__global__ __launch_bounds__(256)
void fuse_w_kernel(const float* __restrict__ kb, const float* __restrict__ km,
                   unsigned short* __restrict__ wf2)
{
    int idx = blockIdx.x * 256 + threadIdx.x;
    if (idx >= 4 * 4 * 9 * 2 * 64 * 8) return;
    int e  = idx & 7;
    int oc = (idx >> 3) & 63;
    int h  = (idx >> 9) & 1;
    int r  = idx >> 10;          // t + 9*(ck + 4*d)
    int t  = r % 9; r /= 9;
    int ck = r & 3;
    int d  = r >> 2;
    int ic = ck * 16 + h * 8 + e;
    wf2[idx] = f2bf(kb[(oc * ICn + ic) * 9 + t] * km[(d * ICn + ic) * 9 + t]);
}

// ---------------- zero the halo of each (b,ck) plane ----------------
__global__ __launch_bounds__(256)
void pad_zero_kernel(unsigned short* __restrict__ Xt)
{
    const int plane = blockIdx.x;   // 0..255 = b*4+ck
    const int tid = threadIdx.x;
    const size_t base = (size_t)plane * YP * YP * 16;
    const bf8 z = bf8{0,0,0,0,0,0,0,0};
    for (int i = tid; i < YP * 2; i += 256) {
        *reinterpret_cast<bf8*>(Xt + base + (size_t)i * 8) = z;
        *reinterpret_cast<bf8*>(Xt + base + (size_t)113 * YP * 16 + (size_t)i * 8) = z;
    }
    for (int i = tid; i < 112 * 2 * 2; i += 256) {
        int j = i & 1, col = (i >> 1) & 1, yp = 1 + (i >> 2);
        size_t off = base + ((size_t)yp * YP + col * 113) * 16 + (size_t)j * 8;
        *reinterpret_cast<bf8*>(Xt + off) = z;
    }
}

// ---- transpose x[b][ic][y][x] fp32 -> Xt[b][ic/16][y+1][x+1][ic%16] bf16 ----
__global__ __launch_bounds__(256, 4)
void transpose_kernel(const float* __restrict__ x, unsigned short* __restrict__ Xt)
{
    __shared__ unsigned short T[56][68];
    const int tid = threadIdx.x;
    const int xh = blockIdx.x;      // 0..1 -> x0 = 0,56
    const int y  = blockIdx.y;      // 0..111
    const int b  = blockIdx.z;      // 0..63
    const int x0 = xh * 56;

    for (int i = tid; i < 64 * 14; i += 256) {       // 64 ic x 14 float4
        int ic = i / 14, c4 = i - ic * 14;
        const float4* p = reinterpret_cast<const float4*>(
            x + (((size_t)b * ICn + ic) * HH + y) * WW + x0 + c4 * 4);
        float4 v = *p;
        T[c4 * 4 + 0][ic] = f2bf(v.x);
        T[c4 * 4 + 1][ic] = f2bf(v.y);
        T[c4 * 4 + 2][ic] = f2bf(v.z);
        T[c4 * 4 + 3][ic] = f2bf(v.w);
    }
    __syncthreads();
    for (int i = tid; i < 56 * 16; i += 256) {       // 56 x  x 16 bf4
        int xx = i >> 4, k = i & 15;
        bf4 w = *reinterpret_cast<bf4*>(&T[xx][k * 4]);
        int ck = k >> 2, q = k & 3;
        *reinterpret_cast<bf4*>(
            Xt + ((((size_t)b * 4 + ck) * YP + y + 1) * YP + (x0 + xx + 1)) * 16 + q * 4) = w;
    }
}

// ------- main: implicit GEMM, m97-shape 2x2 wave tile, per-ck dbuf -------
__global__ __launch_bounds__(256, 2)
void adaconv_main(const unsigned short* __restrict__ Xt,
                  const unsigned short* __restrict__ wf2,
                  const int* __restrict__ label,
                  const int* __restrict__ epoch,
                  float* __restrict__ out)
{
    __shared__ unsigned short L[2][TCHK * 8];   // 2 x 31104 B

    const int tid  = threadIdx.x;
    const int b    = blockIdx.y;
    const int xt   = blockIdx.x & 1;     // x0 = 0 or 64
    const int yt   = blockIdx.x >> 1;    // 0..27
    const int x0 = xt * 64, y0 = yt * 4;
    const int w    = tid >> 6;           // wave 0..3 = output row y0+w
    const int lane = tid & 63;
    const int ln   = lane & 31;
    const int h    = lane >> 5;          // K-half

    int d = (epoch[0] >= FUSE_EPOCH) ? 0 : label[b];
    d &= 3;

    // ---- precompute staging sources (per-thread, ck-stepped) ----
    const unsigned short* gaddr[8];
    unsigned gstep[8];
    #pragma unroll
    for (int r = 0; r < 8; ++r) {
        int c = r * 256 + tid;
        if (c < BCHK) {
            int i   = c / 132;
            int rem = c - i * 132;
            int hh  = rem / 66;
            int px  = rem - hh * 66;
            int xp = x0 + px; if (xp > 113) xp = 113;
            gaddr[r] = Xt + (((size_t)b * 4 * YP + (y0 + i)) * YP + xp) * 16 + hh * 8;
            gstep[r] = YP * YP * 16;
        } else {
            int ca = c - BCHK;           // may exceed ACHK for r==7 tail (masked)
            int t  = (ca >> 7) & 15;
            int hh = (ca >> 6) & 1;
            int oc = ca & 63;
            gaddr[r] = wf2 + (size_t)d * 36864 + t * 1024 + hh * 512 + oc * 8;
            gstep[r] = 9216;
        }
    }

    auto stage = [&](int buf) {
        #pragma unroll
        for (int r = 0; r < 8; ++r) {
            if (r * 256 + tid < TCHK) {
                gload16(gaddr[r], &L[buf][(r * 256 + w * 64) * 8]);
                gaddr[r] += gstep[r];
            }
        }
    };

    f32x16 acc[2][2];
    #pragma unroll
    for (int m = 0; m < 2; ++m)
        #pragma unroll
        for (int j = 0; j < 2; ++j)
            #pragma unroll
            for (int k = 0; k < 16; ++k) acc[m][j][k] = 0.f;

    // frag base element offsets within a buffer
    // B elem = ((w+kh)*2 + h)*66*8 + (j*32+ln+kw)*8  = bb + j*256 + (kh*132+kw)*8
    const int bb  = (w * 132 + h * 66 + ln) * 8;
    // A elem = 792*8 + (t*2+h)*64*8 + (m*32+ln)*8    = ab + m*256 + t*1024
    const int ab  = 6336 + h * 512 + ln * 8;

    stage(0);
    __syncthreads();

    int cur = 0;
    #pragma unroll
    for (int ck = 0; ck < 4; ++ck) {
        if (ck < 3) stage(cur ^ 1);

        const unsigned short* Lc = L[cur];
        #pragma unroll
        for (int kh = 0; kh < 3; ++kh) {
            #pragma unroll
            for (int kw = 0; kw < 3; ++kw) {
                const int t = kh * 3 + kw;
                short8 a0 = *reinterpret_cast<const short8*>(&Lc[ab + t * 1024]);
                short8 a1 = *reinterpret_cast<const short8*>(&Lc[ab + 256 + t * 1024]);
                short8 b0 = *reinterpret_cast<const short8*>(&Lc[bb + (kh * 132 + kw) * 8]);
                short8 b1 = *reinterpret_cast<const short8*>(&Lc[bb + 256 + (kh * 132 + kw) * 8]);
                acc[0][0] = __builtin_amdgcn_mfma_f32_32x32x16_bf16(a0, b0, acc[0][0], 0, 0, 0);
                acc[0][1] = __builtin_amdgcn_mfma_f32_32x32x16_bf16(a0, b1, acc[0][1], 0, 0, 0);
                acc[1][0] = __builtin_amdgcn_mfma_f32_32x32x16_bf16(a1, b0, acc[1][0], 0, 0, 0);
                acc[1][1] = __builtin_amdgcn_mfma_f32_32x32x16_bf16(a1, b1, acc[1][1], 0, 0, 0);
            }
        }
        __syncthreads();   // drains stage(ck+1); WAR guard
        cur ^= 1;
    }

    // ---- store: oc = m*32 + (reg&3) + 8*(reg>>2) + 4*h ; px = x0+j*32+ln ----
    #pragma unroll
    for (int m = 0; m < 2; ++m) {
        #pragma unroll
        for (int j = 0; j < 2; ++j) {
            if (xt == 1 && j == 1 && ln >= 16) continue;   // px >= 112
            float* ob = out + ((size_t)(b * OCn + m * 32 + 4 * h)) * NPIX
                            + (y0 + w) * WW + x0 + j * 32 + ln;
            #pragma unroll
            for (int reg = 0; reg < 16; ++reg) {
                int row = (reg & 3) + 8 * (reg >> 2);
                ob[(size_t)row * NPIX] = acc[m][j][reg];
            }
        }
    }
}

// ---------------- fallback (round-5 structure, no ws) ----------------
#define ICP 24
#define WSTRIDE 152
__global__ __launch_bounds__(256, 2)
void adaconv_fallback(const float* __restrict__ x,
                      const float* __restrict__ kb,
                      const float* __restrict__ km,
                      const int* __restrict__ label,
                      const int* __restrict__ epoch,
                      float* __restrict__ out)
{
    __shared__ unsigned short Xs[18][34][ICP];
    __shared__ unsigned short Ws[64][WSTRIDE];

    const int tid = threadIdx.x;
    const int b   = blockIdx.y;
    const int bx  = blockIdx.x & 3;
    const int byy = blockIdx.x >> 2;
    const int x0 = bx * 32, y0 = byy * 16;

    int d = (epoch[0] >= FUSE_EPOCH) ? 0 : label[b];
    d &= 3;

    const int w    = tid >> 6;
    const int lane = tid & 63;
    const int ln   = lane & 31;
    const int h    = lane >> 5;

    f32x16 acc[2][4];
    #pragma unroll
    for (int m = 0; m < 2; ++m)
        #pragma unroll
        for (int j = 0; j < 4; ++j)
            #pragma unroll
            for (int k = 0; k < 16; ++k) acc[m][j][k] = 0.f;

    const float* xb = x + (size_t)b * ICn * HH * WW;

    for (int ck = 0; ck < 4; ++ck) {
        const int icb = ck * 16;
        __syncthreads();
        for (int idx = tid; idx < 18 * 34 * 16; idx += 256) {
            int ic  = idx / 612;
            int rem = idx - ic * 612;
            int r   = rem / 34;
            int c   = rem - r * 34;
            int gy = y0 - 1 + r, gx = x0 - 1 + c;
            float v = 0.f;
            if ((unsigned)gy < HH && (unsigned)gx < WW)
                v = xb[(size_t)(icb + ic) * (HH * WW) + gy * WW + gx];
            Xs[r][c][ic] = f2bf(v);
        }
        for (int i = tid; i < 9216; i += 256) {
            int ic_ = i & 15;
            int tt  = (i >> 4) % 9;
            int oc  = i / 144;
            int ic  = icb + ic_;
            Ws[oc][tt * 16 + ic_] = f2bf(kb[(oc * ICn + ic) * 9 + tt] * km[(d * ICn + ic) * 9 + tt]);
        }
        __syncthreads();
        #pragma unroll
        for (int kh = 0; kh < 3; ++kh)
            #pragma unroll
            for (int kw = 0; kw < 3; ++kw) {
                const int t = kh * 3 + kw;
                short8 a0 = *reinterpret_cast<const short8*>(&Ws[ln][t * 16 + h * 8]);
                short8 a1 = *reinterpret_cast<const short8*>(&Ws[32 + ln][t * 16 + h * 8]);
                #pragma unroll
                for (int rj = 0; rj < 4; ++rj) {
                    short8 bb2 = *reinterpret_cast<const short8*>(&Xs[4 * w + rj + kh][ln + kw][h * 8]);
                    acc[0][rj] = __builtin_amdgcn_mfma_f32_32x32x16_bf16(a0, bb2, acc[0][rj], 0, 0, 0);
                    acc[1][rj] = __builtin_amdgcn_mfma_f32_32x32x16_bf16(a1, bb2, acc[1][rj], 0, 0, 0);
                }
            }
    }

    const int xg = x0 + ln;
    if (xg < WW) {
        #pragma unroll
        for (int m = 0; m < 2; ++m)
            #pragma unroll
            for (int rj = 0; rj < 4; ++rj) {
                const int yg = y0 + 4 * w + rj;
                #pragma unroll
                for (int reg = 0; reg < 16; ++reg) {
                    const int row = (reg & 3) + 8 * (reg >> 2) + 4 * h;
                    out[(((size_t)b * OCn + m * 32 + row) * HH + yg) * WW + xg] = acc[m][rj][reg];
                }
            }
    }
}

extern "C" void kernel_launch(void* const* d_in, const int* in_sizes, int n_in,
                              void* d_out, int out_size, void* d_ws, size_t ws_size,
                              hipStream_t stream) {
    const float* x  = (const float*)d_in[0];
    const float* kb = (const float*)d_in[1];
    const float* km = (const float*)d_in[2];
    const int*   lb = (const int*)d_in[3];
    const int*   ep = (const int*)d_in[4];
    float* out = (float*)d_out;

    if (ws_size >= XT_BYTES + WF_BYTES) {
        unsigned short* Xt  = (unsigned short*)d_ws;
        unsigned short* wf2 = (unsigned short*)((char*)d_ws + XT_BYTES);
        fuse_w_kernel<<<576, 256, 0, stream>>>(kb, km, wf2);
        pad_zero_kernel<<<256, 256, 0, stream>>>(Xt);
        transpose_kernel<<<dim3(2, HH, 64), 256, 0, stream>>>(x, Xt);
        adaconv_main<<<dim3(56, 64), 256, 0, stream>>>(Xt, wf2, lb, ep, out);
    } else {
        adaconv_fallback<<<dim3(28, 64), 256, 0, stream>>>(x, kb, km, lb, ep, out);
    }
}

// Round 19
// 174.900 us; speedup vs baseline: 1.8410x; 1.0347x over previous
//
#include <hip/hip_runtime.h>
#include <hip/hip_bf16.h>

// AdaConv2d: per-sample conv, kernel = base * mask[label[b]] (oc-indep mask).
// B=64, IC=OC=64, H=W=112, 3x3, pad 1. fp32 in/out.
//
// Round 18: fatter blocks + better reuse. R11-R17 wall at ~116us: 14 serial
// block-rounds/CU x (prologue+4 barrier drains+epilogue) and 1.0 ds_read/MFMA
// (A re-read per tap -> LDS stream ~40us). New: block = 4rows x FULL 112px x
// 64oc, acc 2x4 (128 AGPR), 6 reads->8 MFMAs per tap (0.75), grid 1792 ->
// 7 rounds/CU, staging has zero clamps (full padded rows). LDS 2x40.3KB ->
// 2 blocks/CU. Same 2-phase stage-ahead + per-ck __syncthreads.

#define HH 112
#define WW 112
#define ICn 64
#define OCn 64
#define FUSE_EPOCH 9
#define NPIX (HH * WW)
#define YP 114

#define BCH2 1368          // B chunks: 6 rows x 2 hh x 114 px
#define ACH2 1152          // A chunks: 9 t x 2 hh x 64 oc (per ck)
#define TCH2 (BCH2 + ACH2) // 2520 chunks x 16B = 40320 B per buffer
#define ABASE (BCH2 * 8)   // element offset of A region

typedef __attribute__((ext_vector_type(8)))  short  short8;
typedef __attribute__((ext_vector_type(8)))  unsigned short bf8;
typedef __attribute__((ext_vector_type(4)))  unsigned short bf4;
typedef __attribute__((ext_vector_type(16))) float  f32x16;
typedef unsigned int u32;

#define XT_ELEMS ((size_t)64 * 4 * YP * YP * 16)
#define XT_BYTES (XT_ELEMS * 2)
#define WF_BYTES ((size_t)4 * 64 * 576 * 2)

static __device__ __forceinline__ unsigned short f2bf(float v) {
    __hip_bfloat16 hb = __float2bfloat16(v);
    return *reinterpret_cast<unsigned short*>(&hb);
}

static __device__ __forceinline__ void gload16(const unsigned short* g, unsigned short* l) {
    __builtin_amdgcn_global_load_lds(
        (const __attribute__((address_space(1))) u32*)g,
        (__attribute__((address_space(3))) u32*)l, 16, 0, 0);
}

// -------- fused weights: wf2[d][ck][t][h][oc][8e], ic = ck*16+h*8+e --------
__global__ __launch_bounds__(256)
void fuse_w_kernel(const float* __restrict__ kb, const float* __restrict__ km,
                   unsigned short* __restrict__ wf2)
{
    int idx = blockIdx.x * 256 + threadIdx.x;
    if (idx >= 4 * 4 * 9 * 2 * 64 * 8) return;
    int e  = idx & 7;
    int oc = (idx >> 3) & 63;
    int h  = (idx >> 9) & 1;
    int r  = idx >> 10;          // t + 9*(ck + 4*d)
    int t  = r % 9; r /= 9;
    int ck = r & 3;
    int d  = r >> 2;
    int ic = ck * 16 + h * 8 + e;
    wf2[idx] = f2bf(kb[(oc * ICn + ic) * 9 + t] * km[(d * ICn + ic) * 9 + t]);
}

// ---------------- zero the halo of each (b,ck) plane ----------------
__global__ __launch_bounds__(256)
void pad_zero_kernel(unsigned short* __restrict__ Xt)
{
    const int plane = blockIdx.x;   // 0..255 = b*4+ck
    const int tid = threadIdx.x;
    const size_t base = (size_t)plane * YP * YP * 16;
    const bf8 z = bf8{0,0,0,0,0,0,0,0};
    for (int i = tid; i < YP * 2; i += 256) {
        *reinterpret_cast<bf8*>(Xt + base + (size_t)i * 8) = z;
        *reinterpret_cast<bf8*>(Xt + base + (size_t)113 * YP * 16 + (size_t)i * 8) = z;
    }
    for (int i = tid; i < 112 * 2 * 2; i += 256) {
        int j = i & 1, col = (i >> 1) & 1, yp = 1 + (i >> 2);
        size_t off = base + ((size_t)yp * YP + col * 113) * 16 + (size_t)j * 8;
        *reinterpret_cast<bf8*>(Xt + off) = z;
    }
}

// ---- transpose x[b][ic][y][x] fp32 -> Xt[b][ic/16][y+1][x+1][ic%16] bf16 ----
__global__ __launch_bounds__(256, 4)
void transpose_kernel(const float* __restrict__ x, unsigned short* __restrict__ Xt)
{
    __shared__ unsigned short T[56][68];
    const int tid = threadIdx.x;
    const int xh = blockIdx.x;      // 0..1 -> x0 = 0,56
    const int y  = blockIdx.y;      // 0..111
    const int b  = blockIdx.z;      // 0..63
    const int x0 = xh * 56;

    for (int i = tid; i < 64 * 14; i += 256) {       // 64 ic x 14 float4
        int ic = i / 14, c4 = i - ic * 14;
        const float4* p = reinterpret_cast<const float4*>(
            x + (((size_t)b * ICn + ic) * HH + y) * WW + x0 + c4 * 4);
        float4 v = *p;
        T[c4 * 4 + 0][ic] = f2bf(v.x);
        T[c4 * 4 + 1][ic] = f2bf(v.y);
        T[c4 * 4 + 2][ic] = f2bf(v.z);
        T[c4 * 4 + 3][ic] = f2bf(v.w);
    }
    __syncthreads();
    for (int i = tid; i < 56 * 16; i += 256) {       // 56 x  x 16 bf4
        int xx = i >> 4, k = i & 15;
        bf4 w = *reinterpret_cast<bf4*>(&T[xx][k * 4]);
        int ck = k >> 2, q = k & 3;
        *reinterpret_cast<bf4*>(
            Xt + ((((size_t)b * 4 + ck) * YP + y + 1) * YP + (x0 + xx + 1)) * 16 + q * 4) = w;
    }
}

// -- main: implicit GEMM, 4rows x 112px x 64oc blocks, 2x4 acc, per-ck dbuf --
__global__ __launch_bounds__(256, 2)
void adaconv_main(const unsigned short* __restrict__ Xt,
                  const unsigned short* __restrict__ wf2,
                  const int* __restrict__ label,
                  const int* __restrict__ epoch,
                  float* __restrict__ out)
{
    __shared__ unsigned short L[2][TCH2 * 8];   // 2 x 40320 B

    const int tid  = threadIdx.x;
    const int b    = blockIdx.y;
    const int yt   = blockIdx.x;         // 0..27
    const int y0   = yt * 4;
    const int w    = tid >> 6;           // wave 0..3 = output row y0+w
    const int lane = tid & 63;
    const int ln   = lane & 31;
    const int h    = lane >> 5;          // K-half

    int d = (epoch[0] >= FUSE_EPOCH) ? 0 : label[b];
    d &= 3;

    // ---- precompute staging sources (per-thread, ck-stepped) ----
    const unsigned short* gaddr[10];
    unsigned gstep[10];
    #pragma unroll
    for (int r = 0; r < 10; ++r) {
        int c = r * 256 + tid;
        if (c < BCH2) {
            int i   = c / 228;
            int rem = c - i * 228;
            int hh  = rem / 114;
            int px  = rem - hh * 114;          // 0..113, no clamp
            gaddr[r] = Xt + (((size_t)b * 4 * YP + (y0 + i)) * YP + px) * 16 + hh * 8;
            gstep[r] = YP * YP * 16;
        } else if (c < TCH2) {
            int ca = c - BCH2;
            int t  = ca >> 7;
            int hh = (ca >> 6) & 1;
            int oc = ca & 63;
            gaddr[r] = wf2 + (size_t)d * 36864 + t * 1024 + hh * 512 + oc * 8;
            gstep[r] = 9216;
        } else {
            gaddr[r] = wf2; gstep[r] = 0;      // masked at issue
        }
    }

    auto stage = [&](int buf) {
        #pragma unroll
        for (int r = 0; r < 10; ++r) {
            if (r * 256 + tid < TCH2) {
                gload16(gaddr[r], &L[buf][(r * 256 + w * 64) * 8]);
                gaddr[r] += gstep[r];
            }
        }
    };

    f32x16 acc[2][4];
    #pragma unroll
    for (int m = 0; m < 2; ++m)
        #pragma unroll
        for (int j = 0; j < 4; ++j)
            #pragma unroll
            for (int k = 0; k < 16; ++k) acc[m][j][k] = 0.f;

    // element-offset bases
    const int bb = (w * 228 + h * 114 + ln) * 8;   // + (kh*228+kw)*8 + j*256
    const int ab = ABASE + h * 512 + ln * 8;       // + m*256 + t*1024

    stage(0);
    __syncthreads();

    int cur = 0;
    #pragma unroll
    for (int ck = 0; ck < 4; ++ck) {
        if (ck < 3) stage(cur ^ 1);

        const unsigned short* Lc = L[cur];
        #pragma unroll
        for (int kh = 0; kh < 3; ++kh) {
            #pragma unroll
            for (int kw = 0; kw < 3; ++kw) {
                const int t = kh * 3 + kw;
                short8 a0 = *reinterpret_cast<const short8*>(&Lc[ab + t * 1024]);
                short8 a1 = *reinterpret_cast<const short8*>(&Lc[ab + 256 + t * 1024]);
                #pragma unroll
                for (int j = 0; j < 4; ++j) {
                    short8 bj = *reinterpret_cast<const short8*>(
                        &Lc[bb + (kh * 228 + kw + j * 32) * 8]);
                    acc[0][j] = __builtin_amdgcn_mfma_f32_32x32x16_bf16(a0, bj, acc[0][j], 0, 0, 0);
                    acc[1][j] = __builtin_amdgcn_mfma_f32_32x32x16_bf16(a1, bj, acc[1][j], 0, 0, 0);
                }
            }
        }
        __syncthreads();   // drains stage(ck+1); WAR guard
        cur ^= 1;
    }

    // ---- store: oc = m*32 + (reg&3) + 8*(reg>>2) + 4*h ; px = j*32+ln ----
    #pragma unroll
    for (int m = 0; m < 2; ++m) {
        #pragma unroll
        for (int j = 0; j < 4; ++j) {
            if (j == 3 && ln >= 16) continue;   // px >= 112
            float* ob = out + ((size_t)(b * OCn + m * 32 + 4 * h)) * NPIX
                            + (y0 + w) * WW + j * 32 + ln;
            #pragma unroll
            for (int reg = 0; reg < 16; ++reg) {
                int row = (reg & 3) + 8 * (reg >> 2);
                ob[(size_t)row * NPIX] = acc[m][j][reg];
            }
        }
    }
}

// ---------------- fallback (round-5 structure, no ws) ----------------
#define ICP 24
#define WSTRIDE 152
__global__ __launch_bounds__(256, 2)
void adaconv_fallback(const float* __restrict__ x,
                      const float* __restrict__ kb,
                      const float* __restrict__ km,
                      const int* __restrict__ label,
                      const int* __restrict__ epoch,
                      float* __restrict__ out)
{
    __shared__ unsigned short Xs[18][34][ICP];
    __shared__ unsigned short Ws[64][WSTRIDE];

    const int tid = threadIdx.x;
    const int b   = blockIdx.y;
    const int bx  = blockIdx.x & 3;
    const int byy = blockIdx.x >> 2;
    const int x0 = bx * 32, y0 = byy * 16;

    int d = (epoch[0] >= FUSE_EPOCH) ? 0 : label[b];
    d &= 3;

    const int w    = tid >> 6;
    const int lane = tid & 63;
    const int ln   = lane & 31;
    const int h    = lane >> 5;

    f32x16 acc[2][4];
    #pragma unroll
    for (int m = 0; m < 2; ++m)
        #pragma unroll
        for (int j = 0; j < 4; ++j)
            #pragma unroll
            for (int k = 0; k < 16; ++k) acc[m][j][k] = 0.f;

    const float* xb = x + (size_t)b * ICn * HH * WW;

    for (int ck = 0; ck < 4; ++ck) {
        const int icb = ck * 16;
        __syncthreads();
        for (int idx = tid; idx < 18 * 34 * 16; idx += 256) {
            int ic  = idx / 612;
            int rem = idx - ic * 612;
            int r   = rem / 34;
            int c   = rem - r * 34;
            int gy = y0 - 1 + r, gx = x0 - 1 + c;
            float v = 0.f;
            if ((unsigned)gy < HH && (unsigned)gx < WW)
                v = xb[(size_t)(icb + ic) * (HH * WW) + gy * WW + gx];
            Xs[r][c][ic] = f2bf(v);
        }
        for (int i = tid; i < 9216; i += 256) {
            int ic_ = i & 15;
            int tt  = (i >> 4) % 9;
            int oc  = i / 144;
            int ic  = icb + ic_;
            Ws[oc][tt * 16 + ic_] = f2bf(kb[(oc * ICn + ic) * 9 + tt] * km[(d * ICn + ic) * 9 + tt]);
        }
        __syncthreads();
        #pragma unroll
        for (int kh = 0; kh < 3; ++kh)
            #pragma unroll
            for (int kw = 0; kw < 3; ++kw) {
                const int t = kh * 3 + kw;
                short8 a0 = *reinterpret_cast<const short8*>(&Ws[ln][t * 16 + h * 8]);
                short8 a1 = *reinterpret_cast<const short8*>(&Ws[32 + ln][t * 16 + h * 8]);
                #pragma unroll
                for (int rj = 0; rj < 4; ++rj) {
                    short8 bb2 = *reinterpret_cast<const short8*>(&Xs[4 * w + rj + kh][ln + kw][h * 8]);
                    acc[0][rj] = __builtin_amdgcn_mfma_f32_32x32x16_bf16(a0, bb2, acc[0][rj], 0, 0, 0);
                    acc[1][rj] = __builtin_amdgcn_mfma_f32_32x32x16_bf16(a1, bb2, acc[1][rj], 0, 0, 0);
                }
            }
    }

    const int xg = x0 + ln;
    if (xg < WW) {
        #pragma unroll
        for (int m = 0; m < 2; ++m)
            #pragma unroll
            for (int rj = 0; rj < 4; ++rj) {
                const int yg = y0 + 4 * w + rj;
                #pragma unroll
                for (int reg = 0; reg < 16; ++reg) {
                    const int row = (reg & 3) + 8 * (reg >> 2) + 4 * h;
                    out[(((size_t)b * OCn + m * 32 + row) * HH + yg) * WW + xg] = acc[m][rj][reg];
                }
            }
    }
}

extern "C" void kernel_launch(void* const* d_in, const int* in_sizes, int n_in,
                              void* d_out, int out_size, void* d_ws, size_t ws_size,
                              hipStream_t stream) {
    const float* x  = (const float*)d_in[0];
    const float* kb = (const float*)d_in[1];
    const float* km = (const float*)d_in[2];
    const int*   lb = (const int*)d_in[3];
    const int*   ep = (const int*)d_in[4];
    float* out = (float*)d_out;

    if (ws_size >= XT_BYTES + WF_BYTES) {
        unsigned short* Xt  = (unsigned short*)d_ws;
        unsigned short* wf2 = (unsigned short*)((char*)d_ws + XT_BYTES);
        fuse_w_kernel<<<576, 256, 0, stream>>>(kb, km, wf2);
        pad_zero_kernel<<<256, 256, 0, stream>>>(Xt);
        transpose_kernel<<<dim3(2, HH, 64), 256, 0, stream>>>(x, Xt);
        adaconv_main<<<dim3(28, 64), 256, 0, stream>>>(Xt, wf2, lb, ep, out);
    } else {
        adaconv_fallback<<<dim3(28, 64), 256, 0, stream>>>(x, kb, km, lb, ep, out);
    }
}

// Round 20
// 173.751 us; speedup vs baseline: 1.8531x; 1.0066x over previous
//
#include <hip/hip_runtime.h>
#include <hip/hip_bf16.h>

// AdaConv2d: per-sample conv, kernel = base * mask[label[b]] (oc-indep mask).
// B=64, IC=OC=64, H=W=112, 3x3, pad 1. fp32 in/out.
//
// Round 19: R18 geometry + T4 counted-vmcnt pipeline (m201 template).
// R18's per-ck __syncthreads drained all 10 in-flight next-stage loads
// (vmcnt(0)) -> next-tile HBM latency serialized with compute, 4x per block.
// Now: stage(next) [exactly 10 gload_lds per wave, uniform] ->
// s_waitcnt vmcnt(10) [prev stage complete, next stays in flight] ->
// raw s_barrier -> sched_barrier(0) -> compute -> raw s_barrier (WAR).
// Register state identical to R18 (acc 2x4 = 128 AGPR, ~100 VGPR, no spill).

#define HH 112
#define WW 112
#define ICn 64
#define OCn 64
#define FUSE_EPOCH 9
#define NPIX (HH * WW)
#define YP 114

#define BCH2 1368          // B chunks: 6 rows x 2 hh x 114 px
#define ACH2 1152          // A chunks: 9 t x 2 hh x 64 oc (per ck)
#define TCH2 (BCH2 + ACH2) // 2520 chunks x 16B = 40320 B per buffer
#define ABASE (BCH2 * 8)   // element offset of A region

typedef __attribute__((ext_vector_type(8)))  short  short8;
typedef __attribute__((ext_vector_type(8)))  unsigned short bf8;
typedef __attribute__((ext_vector_type(4)))  unsigned short bf4;
typedef __attribute__((ext_vector_type(16))) float  f32x16;
typedef unsigned int u32;

#define XT_ELEMS ((size_t)64 * 4 * YP * YP * 16)
#define XT_BYTES (XT_ELEMS * 2)
#define WF_BYTES ((size_t)4 * 64 * 576 * 2)

static __device__ __forceinline__ unsigned short f2bf(float v) {
    __hip_bfloat16 hb = __float2bfloat16(v);
    return *reinterpret_cast<unsigned short*>(&hb);
}

static __device__ __forceinline__ void gload16(const unsigned short* g, unsigned short* l) {
    __builtin_amdgcn_global_load_lds(
        (const __attribute__((address_space(1))) u32*)g,
        (__attribute__((address_space(3))) u32*)l, 16, 0, 0);
}

// -------- fused weights: wf2[d][ck][t][h][oc][8e], ic = ck*16+h*8+e --------
__global__ __launch_bounds__(256)
void fuse_w_kernel(const float* __restrict__ kb, const float* __restrict__ km,
                   unsigned short* __restrict__ wf2)
{
    int idx = blockIdx.x * 256 + threadIdx.x;
    if (idx >= 4 * 4 * 9 * 2 * 64 * 8) return;
    int e  = idx & 7;
    int oc = (idx >> 3) & 63;
    int h  = (idx >> 9) & 1;
    int r  = idx >> 10;          // t + 9*(ck + 4*d)
    int t  = r % 9; r /= 9;
    int ck = r & 3;
    int d  = r >> 2;
    int ic = ck * 16 + h * 8 + e;
    wf2[idx] = f2bf(kb[(oc * ICn + ic) * 9 + t] * km[(d * ICn + ic) * 9 + t]);
}

// ---------------- zero the halo of each (b,ck) plane ----------------
__global__ __launch_bounds__(256)
void pad_zero_kernel(unsigned short* __restrict__ Xt)
{
    const int plane = blockIdx.x;   // 0..255 = b*4+ck
    const int tid = threadIdx.x;
    const size_t base = (size_t)plane * YP * YP * 16;
    const bf8 z = bf8{0,0,0,0,0,0,0,0};
    for (int i = tid; i < YP * 2; i += 256) {
        *reinterpret_cast<bf8*>(Xt + base + (size_t)i * 8) = z;
        *reinterpret_cast<bf8*>(Xt + base + (size_t)113 * YP * 16 + (size_t)i * 8) = z;
    }
    for (int i = tid; i < 112 * 2 * 2; i += 256) {
        int j = i & 1, col = (i >> 1) & 1, yp = 1 + (i >> 2);
        size_t off = base + ((size_t)yp * YP + col * 113) * 16 + (size_t)j * 8;
        *reinterpret_cast<bf8*>(Xt + off) = z;
    }
}

// ---- transpose x[b][ic][y][x] fp32 -> Xt[b][ic/16][y+1][x+1][ic%16] bf16 ----
__global__ __launch_bounds__(256, 4)
void transpose_kernel(const float* __restrict__ x, unsigned short* __restrict__ Xt)
{
    __shared__ unsigned short T[56][68];
    const int tid = threadIdx.x;
    const int xh = blockIdx.x;      // 0..1 -> x0 = 0,56
    const int y  = blockIdx.y;      // 0..111
    const int b  = blockIdx.z;      // 0..63
    const int x0 = xh * 56;

    for (int i = tid; i < 64 * 14; i += 256) {       // 64 ic x 14 float4
        int ic = i / 14, c4 = i - ic * 14;
        const float4* p = reinterpret_cast<const float4*>(
            x + (((size_t)b * ICn + ic) * HH + y) * WW + x0 + c4 * 4);
        float4 v = *p;
        T[c4 * 4 + 0][ic] = f2bf(v.x);
        T[c4 * 4 + 1][ic] = f2bf(v.y);
        T[c4 * 4 + 2][ic] = f2bf(v.z);
        T[c4 * 4 + 3][ic] = f2bf(v.w);
    }
    __syncthreads();
    for (int i = tid; i < 56 * 16; i += 256) {       // 56 x  x 16 bf4
        int xx = i >> 4, k = i & 15;
        bf4 w = *reinterpret_cast<bf4*>(&T[xx][k * 4]);
        int ck = k >> 2, q = k & 3;
        *reinterpret_cast<bf4*>(
            Xt + ((((size_t)b * 4 + ck) * YP + y + 1) * YP + (x0 + xx + 1)) * 16 + q * 4) = w;
    }
}

// -- main: 4rows x 112px x 64oc blocks, 2x4 acc, counted-vmcnt dbuf (T4) --
__global__ __launch_bounds__(256, 2)
void adaconv_main(const unsigned short* __restrict__ Xt,
                  const unsigned short* __restrict__ wf2,
                  const int* __restrict__ label,
                  const int* __restrict__ epoch,
                  float* __restrict__ out)
{
    __shared__ unsigned short L[2][TCH2 * 8];   // 2 x 40320 B

    const int tid  = threadIdx.x;
    const int b    = blockIdx.y;
    const int yt   = blockIdx.x;         // 0..27
    const int y0   = yt * 4;
    const int w    = tid >> 6;           // wave 0..3 = output row y0+w
    const int lane = tid & 63;
    const int ln   = lane & 31;
    const int h    = lane >> 5;          // K-half

    int d = (epoch[0] >= FUSE_EPOCH) ? 0 : label[b];
    d &= 3;

    // ---- precompute staging sources (per-thread, ck-stepped) ----
    const unsigned short* gaddr[10];
    unsigned gstep[10];
    #pragma unroll
    for (int r = 0; r < 10; ++r) {
        int c = r * 256 + tid;
        if (c < BCH2) {
            int i   = c / 228;
            int rem = c - i * 228;
            int hh  = rem / 114;
            int px  = rem - hh * 114;          // 0..113, no clamp
            gaddr[r] = Xt + (((size_t)b * 4 * YP + (y0 + i)) * YP + px) * 16 + hh * 8;
            gstep[r] = YP * YP * 16;
        } else if (c < TCH2) {
            int ca = c - BCH2;
            int t  = ca >> 7;
            int hh = (ca >> 6) & 1;
            int oc = ca & 63;
            gaddr[r] = wf2 + (size_t)d * 36864 + t * 1024 + hh * 512 + oc * 8;
            gstep[r] = 9216;
        } else {
            gaddr[r] = wf2; gstep[r] = 0;      // masked at issue
        }
    }

    // exactly 10 gload_lds per WAVE per stage (r=9 is partially-active but
    // every wave has >=1 active lane there -> uniform vmcnt accounting)
    auto stage = [&](int buf) {
        #pragma unroll
        for (int r = 0; r < 10; ++r) {
            if (r * 256 + tid < TCH2) {
                gload16(gaddr[r], &L[buf][(r * 256 + w * 64) * 8]);
                gaddr[r] += gstep[r];
            }
        }
    };

    f32x16 acc[2][4];
    #pragma unroll
    for (int m = 0; m < 2; ++m)
        #pragma unroll
        for (int j = 0; j < 4; ++j)
            #pragma unroll
            for (int k = 0; k < 16; ++k) acc[m][j][k] = 0.f;

    // element-offset bases
    const int bb = (w * 228 + h * 114 + ln) * 8;   // + (kh*228+kw)*8 + j*256
    const int ab = ABASE + h * 512 + ln * 8;       // + m*256 + t*1024

    stage(0);

    int cur = 0;
    #pragma unroll
    for (int ck = 0; ck < 4; ++ck) {
        if (ck < 3) {
            stage(cur ^ 1);                                   // 10 new gloads
            asm volatile("s_waitcnt vmcnt(10)" ::: "memory"); // prev 10 done
        } else {
            asm volatile("s_waitcnt vmcnt(0)" ::: "memory");
        }
        __builtin_amdgcn_s_barrier();        // all waves' loads for cur landed
        __builtin_amdgcn_sched_barrier(0);

        const unsigned short* Lc = L[cur];
        #pragma unroll
        for (int kh = 0; kh < 3; ++kh) {
            #pragma unroll
            for (int kw = 0; kw < 3; ++kw) {
                const int t = kh * 3 + kw;
                short8 a0 = *reinterpret_cast<const short8*>(&Lc[ab + t * 1024]);
                short8 a1 = *reinterpret_cast<const short8*>(&Lc[ab + 256 + t * 1024]);
                #pragma unroll
                for (int j = 0; j < 4; ++j) {
                    short8 bj = *reinterpret_cast<const short8*>(
                        &Lc[bb + (kh * 228 + kw + j * 32) * 8]);
                    acc[0][j] = __builtin_amdgcn_mfma_f32_32x32x16_bf16(a0, bj, acc[0][j], 0, 0, 0);
                    acc[1][j] = __builtin_amdgcn_mfma_f32_32x32x16_bf16(a1, bj, acc[1][j], 0, 0, 0);
                }
            }
        }
        __builtin_amdgcn_s_barrier();   // WAR: all reads of L[cur] done (no drain)
        cur ^= 1;
    }

    // ---- store: oc = m*32 + (reg&3) + 8*(reg>>2) + 4*h ; px = j*32+ln ----
    #pragma unroll
    for (int m = 0; m < 2; ++m) {
        #pragma unroll
        for (int j = 0; j < 4; ++j) {
            if (j == 3 && ln >= 16) continue;   // px >= 112
            float* ob = out + ((size_t)(b * OCn + m * 32 + 4 * h)) * NPIX
                            + (y0 + w) * WW + j * 32 + ln;
            #pragma unroll
            for (int reg = 0; reg < 16; ++reg) {
                int row = (reg & 3) + 8 * (reg >> 2);
                ob[(size_t)row * NPIX] = acc[m][j][reg];
            }
        }
    }
}

// ---------------- fallback (round-5 structure, no ws) ----------------
#define ICP 24
#define WSTRIDE 152
__global__ __launch_bounds__(256, 2)
void adaconv_fallback(const float* __restrict__ x,
                      const float* __restrict__ kb,
                      const float* __restrict__ km,
                      const int* __restrict__ label,
                      const int* __restrict__ epoch,
                      float* __restrict__ out)
{
    __shared__ unsigned short Xs[18][34][ICP];
    __shared__ unsigned short Ws[64][WSTRIDE];

    const int tid = threadIdx.x;
    const int b   = blockIdx.y;
    const int bx  = blockIdx.x & 3;
    const int byy = blockIdx.x >> 2;
    const int x0 = bx * 32, y0 = byy * 16;

    int d = (epoch[0] >= FUSE_EPOCH) ? 0 : label[b];
    d &= 3;

    const int w    = tid >> 6;
    const int lane = tid & 63;
    const int ln   = lane & 31;
    const int h    = lane >> 5;

    f32x16 acc[2][4];
    #pragma unroll
    for (int m = 0; m < 2; ++m)
        #pragma unroll
        for (int j = 0; j < 4; ++j)
            #pragma unroll
            for (int k = 0; k < 16; ++k) acc[m][j][k] = 0.f;

    const float* xb = x + (size_t)b * ICn * HH * WW;

    for (int ck = 0; ck < 4; ++ck) {
        const int icb = ck * 16;
        __syncthreads();
        for (int idx = tid; idx < 18 * 34 * 16; idx += 256) {
            int ic  = idx / 612;
            int rem = idx - ic * 612;
            int r   = rem / 34;
            int c   = rem - r * 34;
            int gy = y0 - 1 + r, gx = x0 - 1 + c;
            float v = 0.f;
            if ((unsigned)gy < HH && (unsigned)gx < WW)
                v = xb[(size_t)(icb + ic) * (HH * WW) + gy * WW + gx];
            Xs[r][c][ic] = f2bf(v);
        }
        for (int i = tid; i < 9216; i += 256) {
            int ic_ = i & 15;
            int tt  = (i >> 4) % 9;
            int oc  = i / 144;
            int ic  = icb + ic_;
            Ws[oc][tt * 16 + ic_] = f2bf(kb[(oc * ICn + ic) * 9 + tt] * km[(d * ICn + ic) * 9 + tt]);
        }
        __syncthreads();
        #pragma unroll
        for (int kh = 0; kh < 3; ++kh)
            #pragma unroll
            for (int kw = 0; kw < 3; ++kw) {
                const int t = kh * 3 + kw;
                short8 a0 = *reinterpret_cast<const short8*>(&Ws[ln][t * 16 + h * 8]);
                short8 a1 = *reinterpret_cast<const short8*>(&Ws[32 + ln][t * 16 + h * 8]);
                #pragma unroll
                for (int rj = 0; rj < 4; ++rj) {
                    short8 bb2 = *reinterpret_cast<const short8*>(&Xs[4 * w + rj + kh][ln + kw][h * 8]);
                    acc[0][rj] = __builtin_amdgcn_mfma_f32_32x32x16_bf16(a0, bb2, acc[0][rj], 0, 0, 0);
                    acc[1][rj] = __builtin_amdgcn_mfma_f32_32x32x16_bf16(a1, bb2, acc[1][rj], 0, 0, 0);
                }
            }
    }

    const int xg = x0 + ln;
    if (xg < WW) {
        #pragma unroll
        for (int m = 0; m < 2; ++m)
            #pragma unroll
            for (int rj = 0; rj < 4; ++rj) {
                const int yg = y0 + 4 * w + rj;
                #pragma unroll
                for (int reg = 0; reg < 16; ++reg) {
                    const int row = (reg & 3) + 8 * (reg >> 2) + 4 * h;
                    out[(((size_t)b * OCn + m * 32 + row) * HH + yg) * WW + xg] = acc[m][rj][reg];
                }
            }
    }
}

extern "C" void kernel_launch(void* const* d_in, const int* in_sizes, int n_in,
                              void* d_out, int out_size, void* d_ws, size_t ws_size,
                              hipStream_t stream) {
    const float* x  = (const float*)d_in[0];
    const float* kb = (const float*)d_in[1];
    const float* km = (const float*)d_in[2];
    const int*   lb = (const int*)d_in[3];
    const int*   ep = (const int*)d_in[4];
    float* out = (float*)d_out;

    if (ws_size >= XT_BYTES + WF_BYTES) {
        unsigned short* Xt  = (unsigned short*)d_ws;
        unsigned short* wf2 = (unsigned short*)((char*)d_ws + XT_BYTES);
        fuse_w_kernel<<<576, 256, 0, stream>>>(kb, km, wf2);
        pad_zero_kernel<<<256, 256, 0, stream>>>(Xt);
        transpose_kernel<<<dim3(2, HH, 64), 256, 0, stream>>>(x, Xt);
        adaconv_main<<<dim3(28, 64), 256, 0, stream>>>(Xt, wf2, lb, ep, out);
    } else {
        adaconv_fallback<<<dim3(28, 64), 256, 0, stream>>>(x, kb, km, lb, ep, out);
    }
}

// Round 21
// 119.432 us; speedup vs baseline: 2.6960x; 1.4548x over previous
//
#include <hip/hip_runtime.h>
#include <hip/hip_bf16.h>

// AdaConv2d: per-sample conv, kernel = base * mask[label[b]] (oc-indep mask).
// B=64, IC=OC=64, H=W=112, 3x3, pad 1. fp32 in/out.
//
// Round 20: FUSED single main kernel. R11-R19 pinned main at ~105-120us while
// the pipeline still paid a 50us transpose + 212MB Xt round-trip. Now main
// reads x (fp32) directly: per ck, each thread issues 12 coalesced float4
// loads (4 ic x 4 px items) BEFORE compute (T14 async-split, sched_barrier
// pins issue), then converts (__float22bfloat162_rn) and writes b64 into the
// SAME proven LDS layout as R18 ([row][hh][px][8ic]); A weights still via
// global_load_lds. Compute/store code identical to R18. Total HBM traffic
// 589MB -> ~500MB and two kernels+gaps deleted.

#define HH 112
#define WW 112
#define ICn 64
#define OCn 64
#define FUSE_EPOCH 9
#define NPIX (HH * WW)

typedef __attribute__((ext_vector_type(8)))  short  short8;
typedef __attribute__((ext_vector_type(8)))  unsigned short bf8;
typedef __attribute__((ext_vector_type(16))) float  f32x16;
typedef unsigned int u32;

#define WF_BYTES ((size_t)4 * 64 * 576 * 2)

static __device__ __forceinline__ unsigned short f2bf(float v) {
    __hip_bfloat16 hb = __float2bfloat16(v);
    return *reinterpret_cast<unsigned short*>(&hb);
}

static __device__ __forceinline__ void gload16(const unsigned short* g, unsigned short* l) {
    __builtin_amdgcn_global_load_lds(
        (const __attribute__((address_space(1))) u32*)g,
        (__attribute__((address_space(3))) u32*)l, 16, 0, 0);
}

// -------- fused weights: wf2[d][ck][t][h][oc][8e], ic = ck*16+h*8+e --------
__global__ __launch_bounds__(256)
void fuse_w_kernel(const float* __restrict__ kb, const float* __restrict__ km,
                   unsigned short* __restrict__ wf2)
{
    int idx = blockIdx.x * 256 + threadIdx.x;
    if (idx >= 4 * 4 * 9 * 2 * 64 * 8) return;
    int e  = idx & 7;
    int oc = (idx >> 3) & 63;
    int h  = (idx >> 9) & 1;
    int r  = idx >> 10;          // t + 9*(ck + 4*d)
    int t  = r % 9; r /= 9;
    int ck = r & 3;
    int d  = r >> 2;
    int ic = ck * 16 + h * 8 + e;
    wf2[idx] = f2bf(kb[(oc * ICn + ic) * 9 + t] * km[(d * ICn + ic) * 9 + t]);
}

// ------------------- fused main: direct-x implicit GEMM -------------------
__global__ __launch_bounds__(256, 2)
void adaconv_fused(const float* __restrict__ x,
                   const unsigned short* __restrict__ wf2,
                   const int* __restrict__ label,
                   const int* __restrict__ epoch,
                   float* __restrict__ out)
{
    // B: [6 rows][2 hh][114 px][8 ic] bf16 = 21888 B per buffer
    // A: [9 t][2 hh][64 oc][8 e]      bf16 = 18432 B per buffer
    __shared__ unsigned short Bb[2][10944];
    __shared__ unsigned short Ab[2][9216];

    const int tid  = threadIdx.x;
    const int b    = blockIdx.y;
    const int y0   = blockIdx.x * 4;     // 28 y-tiles
    const int w    = tid >> 6;           // wave 0..3 = out-row y0+w
    const int lane = tid & 63;
    const int ln   = lane & 31;
    const int h    = lane >> 5;          // K-half

    int d = (epoch[0] >= FUSE_EPOCH) ? 0 : label[b];
    d &= 3;
    const unsigned short* wfd = wf2 + (size_t)d * 36864;

    // ---- per-thread B-staging descriptors (672 items, 3 rounds) ----
    // item c = (((lr*2+hh)*2 + icq)*28 + seg): 4 ics x 4 px at (row lr, hh)
    const float* ga[12];
    int  lbase[3];
    bool wact[3], gval[3];
    #pragma unroll
    for (int r = 0; r < 3; ++r) {
        int c = r * 256 + tid;
        bool a = (c < 672);
        int cc = a ? c : 671;
        int seg = cc % 28;
        int q   = cc / 28;
        int icq = q & 1;
        int rh  = q >> 1;              // lr*2+hh
        int lr  = rh >> 1;
        int hh  = rh & 1;
        int gy  = y0 - 1 + lr;
        bool v  = ((unsigned)gy < 112u);
        wact[r] = a;
        gval[r] = v;
        lbase[r] = (rh * 114 + 4 * seg + 1) * 8 + icq * 4;
        int icl = hh * 8 + icq * 4;    // ic within 16-chunk
        #pragma unroll
        for (int i = 0; i < 4; ++i)
            ga[r * 4 + i] = x + ((size_t)(b * 64 + icl + i) * 112 + (v ? gy : 0)) * 112 + 4 * seg;
    }

    auto issueA = [&](int buf, int ck1) {
        #pragma unroll
        for (int r = 0; r < 5; ++r) {
            int c = r * 256 + tid;
            if (c < 1152)
                gload16(wfd + ck1 * 9216 + (size_t)c * 8, &Ab[buf][(r * 256 + w * 64) * 8]);
        }
    };

    f32x16 acc[2][4];
    #pragma unroll
    for (int m = 0; m < 2; ++m)
        #pragma unroll
        for (int j = 0; j < 4; ++j)
            #pragma unroll
            for (int k = 0; k < 16; ++k) acc[m][j][k] = 0.f;

    const int bb = (w * 228 + h * 114 + ln) * 8;   // + (kh*228+kw+j*32)*8
    const int ab = h * 512 + ln * 8;               // + m*256 + t*1024

    // ---- prologue: zero edge px {0,113} in both buffers; stage ck=0 ----
    if (tid < 48) {
        int bz = tid / 24, z = tid % 24;
        int rh = z >> 1, px = (z & 1) ? 113 : 0;
        bf8 zz = bf8{0,0,0,0,0,0,0,0};
        *reinterpret_cast<bf8*>(&Bb[bz][(rh * 114 + px) * 8]) = zz;
    }
    {
        float4 vl[12];
        #pragma unroll
        for (int r = 0; r < 3; ++r)
            if (wact[r])
                #pragma unroll
                for (int i = 0; i < 4; ++i)
                    vl[r * 4 + i] = *reinterpret_cast<const float4*>(ga[r * 4 + i]);
        issueA(0, 0);
        // convert + write B(0)
        #pragma unroll
        for (int r = 0; r < 3; ++r) {
            if (!wact[r]) continue;
            float c0[4] = {vl[r*4+0].x, vl[r*4+0].y, vl[r*4+0].z, vl[r*4+0].w};
            float c1[4] = {vl[r*4+1].x, vl[r*4+1].y, vl[r*4+1].z, vl[r*4+1].w};
            float c2[4] = {vl[r*4+2].x, vl[r*4+2].y, vl[r*4+2].z, vl[r*4+2].w};
            float c3[4] = {vl[r*4+3].x, vl[r*4+3].y, vl[r*4+3].z, vl[r*4+3].w};
            #pragma unroll
            for (int p = 0; p < 4; ++p) {
                float f0 = gval[r] ? c0[p] : 0.f;
                float f1 = gval[r] ? c1[p] : 0.f;
                float f2 = gval[r] ? c2[p] : 0.f;
                float f3 = gval[r] ? c3[p] : 0.f;
                __hip_bfloat162 u01 = __float22bfloat162_rn(make_float2(f0, f1));
                __hip_bfloat162 u23 = __float22bfloat162_rn(make_float2(f2, f3));
                uint2 wv;
                wv.x = *reinterpret_cast<unsigned*>(&u01);
                wv.y = *reinterpret_cast<unsigned*>(&u23);
                *reinterpret_cast<uint2*>(&Bb[0][lbase[r] + p * 8]) = wv;
            }
        }
        __syncthreads();
    }

    // ---- main loop: issue(nxt) -> compute(cur) -> cvt+write(nxt) -> barrier
    #pragma unroll
    for (int ck = 0; ck < 4; ++ck) {
        const int cur = ck & 1, nxt = cur ^ 1;
        float4 vl[12];
        if (ck < 3) {
            #pragma unroll
            for (int r = 0; r < 3; ++r)
                if (wact[r])
                    #pragma unroll
                    for (int i = 0; i < 4; ++i)
                        vl[r * 4 + i] = *reinterpret_cast<const float4*>(
                            ga[r * 4 + i] + (size_t)(ck + 1) * 200704);
            issueA(nxt, ck + 1);
            __builtin_amdgcn_sched_barrier(0);   // keep issues above compute
        }

        const unsigned short* Bc = Bb[cur];
        const unsigned short* Ac = Ab[cur];
        #pragma unroll
        for (int kh = 0; kh < 3; ++kh) {
            #pragma unroll
            for (int kw = 0; kw < 3; ++kw) {
                const int t = kh * 3 + kw;
                short8 a0 = *reinterpret_cast<const short8*>(&Ac[ab + t * 1024]);
                short8 a1 = *reinterpret_cast<const short8*>(&Ac[ab + 256 + t * 1024]);
                #pragma unroll
                for (int j = 0; j < 4; ++j) {
                    short8 bj = *reinterpret_cast<const short8*>(
                        &Bc[bb + (kh * 228 + kw + j * 32) * 8]);
                    acc[0][j] = __builtin_amdgcn_mfma_f32_32x32x16_bf16(a0, bj, acc[0][j], 0, 0, 0);
                    acc[1][j] = __builtin_amdgcn_mfma_f32_32x32x16_bf16(a1, bj, acc[1][j], 0, 0, 0);
                }
            }
        }

        if (ck < 3) {
            #pragma unroll
            for (int r = 0; r < 3; ++r) {
                if (!wact[r]) continue;
                float c0[4] = {vl[r*4+0].x, vl[r*4+0].y, vl[r*4+0].z, vl[r*4+0].w};
                float c1[4] = {vl[r*4+1].x, vl[r*4+1].y, vl[r*4+1].z, vl[r*4+1].w};
                float c2[4] = {vl[r*4+2].x, vl[r*4+2].y, vl[r*4+2].z, vl[r*4+2].w};
                float c3[4] = {vl[r*4+3].x, vl[r*4+3].y, vl[r*4+3].z, vl[r*4+3].w};
                #pragma unroll
                for (int p = 0; p < 4; ++p) {
                    float f0 = gval[r] ? c0[p] : 0.f;
                    float f1 = gval[r] ? c1[p] : 0.f;
                    float f2 = gval[r] ? c2[p] : 0.f;
                    float f3 = gval[r] ? c3[p] : 0.f;
                    __hip_bfloat162 u01 = __float22bfloat162_rn(make_float2(f0, f1));
                    __hip_bfloat162 u23 = __float22bfloat162_rn(make_float2(f2, f3));
                    uint2 wv;
                    wv.x = *reinterpret_cast<unsigned*>(&u01);
                    wv.y = *reinterpret_cast<unsigned*>(&u23);
                    *reinterpret_cast<uint2*>(&Bb[nxt][lbase[r] + p * 8]) = wv;
                }
            }
        }
        __syncthreads();
    }

    // ---- store: oc = m*32 + (reg&3) + 8*(reg>>2) + 4*h ; px = j*32+ln ----
    #pragma unroll
    for (int m = 0; m < 2; ++m) {
        #pragma unroll
        for (int j = 0; j < 4; ++j) {
            if (j == 3 && ln >= 16) continue;   // px >= 112
            float* ob = out + ((size_t)(b * OCn + m * 32 + 4 * h)) * NPIX
                            + (y0 + w) * WW + j * 32 + ln;
            #pragma unroll
            for (int reg = 0; reg < 16; ++reg) {
                int row = (reg & 3) + 8 * (reg >> 2);
                ob[(size_t)row * NPIX] = acc[m][j][reg];
            }
        }
    }
}

// ---------------- fallback (round-5 structure, no ws) ----------------
#define ICP 24
#define WSTRIDE 152
__global__ __launch_bounds__(256, 2)
void adaconv_fallback(const float* __restrict__ x,
                      const float* __restrict__ kb,
                      const float* __restrict__ km,
                      const int* __restrict__ label,
                      const int* __restrict__ epoch,
                      float* __restrict__ out)
{
    __shared__ unsigned short Xs[18][34][ICP];
    __shared__ unsigned short Ws[64][WSTRIDE];

    const int tid = threadIdx.x;
    const int b   = blockIdx.y;
    const int bx  = blockIdx.x & 3;
    const int byy = blockIdx.x >> 2;
    const int x0 = bx * 32, y0 = byy * 16;

    int d = (epoch[0] >= FUSE_EPOCH) ? 0 : label[b];
    d &= 3;

    const int w    = tid >> 6;
    const int lane = tid & 63;
    const int ln   = lane & 31;
    const int h    = lane >> 5;

    f32x16 acc[2][4];
    #pragma unroll
    for (int m = 0; m < 2; ++m)
        #pragma unroll
        for (int j = 0; j < 4; ++j)
            #pragma unroll
            for (int k = 0; k < 16; ++k) acc[m][j][k] = 0.f;

    const float* xb = x + (size_t)b * ICn * HH * WW;

    for (int ck = 0; ck < 4; ++ck) {
        const int icb = ck * 16;
        __syncthreads();
        for (int idx = tid; idx < 18 * 34 * 16; idx += 256) {
            int ic  = idx / 612;
            int rem = idx - ic * 612;
            int r   = rem / 34;
            int c   = rem - r * 34;
            int gy = y0 - 1 + r, gx = x0 - 1 + c;
            float v = 0.f;
            if ((unsigned)gy < HH && (unsigned)gx < WW)
                v = xb[(size_t)(icb + ic) * (HH * WW) + gy * WW + gx];
            Xs[r][c][ic] = f2bf(v);
        }
        for (int i = tid; i < 9216; i += 256) {
            int ic_ = i & 15;
            int tt  = (i >> 4) % 9;
            int oc  = i / 144;
            int ic  = icb + ic_;
            Ws[oc][tt * 16 + ic_] = f2bf(kb[(oc * ICn + ic) * 9 + tt] * km[(d * ICn + ic) * 9 + tt]);
        }
        __syncthreads();
        #pragma unroll
        for (int kh = 0; kh < 3; ++kh)
            #pragma unroll
            for (int kw = 0; kw < 3; ++kw) {
                const int t = kh * 3 + kw;
                short8 a0 = *reinterpret_cast<const short8*>(&Ws[ln][t * 16 + h * 8]);
                short8 a1 = *reinterpret_cast<const short8*>(&Ws[32 + ln][t * 16 + h * 8]);
                #pragma unroll
                for (int rj = 0; rj < 4; ++rj) {
                    short8 bb2 = *reinterpret_cast<const short8*>(&Xs[4 * w + rj + kh][ln + kw][h * 8]);
                    acc[0][rj] = __builtin_amdgcn_mfma_f32_32x32x16_bf16(a0, bb2, acc[0][rj], 0, 0, 0);
                    acc[1][rj] = __builtin_amdgcn_mfma_f32_32x32x16_bf16(a1, bb2, acc[1][rj], 0, 0, 0);
                }
            }
    }

    const int xg = x0 + ln;
    if (xg < WW) {
        #pragma unroll
        for (int m = 0; m < 2; ++m)
            #pragma unroll
            for (int rj = 0; rj < 4; ++rj) {
                const int yg = y0 + 4 * w + rj;
                #pragma unroll
                for (int reg = 0; reg < 16; ++reg) {
                    const int row = (reg & 3) + 8 * (reg >> 2) + 4 * h;
                    out[(((size_t)b * OCn + m * 32 + row) * HH + yg) * WW + xg] = acc[m][rj][reg];
                }
            }
    }
}

extern "C" void kernel_launch(void* const* d_in, const int* in_sizes, int n_in,
                              void* d_out, int out_size, void* d_ws, size_t ws_size,
                              hipStream_t stream) {
    const float* x  = (const float*)d_in[0];
    const float* kb = (const float*)d_in[1];
    const float* km = (const float*)d_in[2];
    const int*   lb = (const int*)d_in[3];
    const int*   ep = (const int*)d_in[4];
    float* out = (float*)d_out;

    if (ws_size >= WF_BYTES) {
        unsigned short* wf2 = (unsigned short*)d_ws;
        fuse_w_kernel<<<576, 256, 0, stream>>>(kb, km, wf2);
        adaconv_fused<<<dim3(28, 64), 256, 0, stream>>>(x, wf2, lb, ep, out);
    } else {
        adaconv_fallback<<<dim3(28, 64), 256, 0, stream>>>(x, kb, km, lb, ep, out);
    }
}